// Round 19
// baseline (238.903 us; speedup 1.0000x reference)
//
#include <hip/hip_runtime.h>
#include <math.h>

constexpr int IN_DIM = 256;
constexpr int HID    = 64;
constexpr int OUTD   = 32;
#define NEG_SLOPE 0.2f
#define EPSV 1e-16f

__device__ __forceinline__ float eluf(float x) {
    return x > 0.f ? x : expm1f(x);
}

__device__ __forceinline__ unsigned short f32_to_bf16_rne(float f) {
    unsigned u = __float_as_uint(f);
    unsigned r = u + 0x7fffu + ((u >> 16) & 1u);
    return (unsigned short)(r >> 16);
}
__device__ __forceinline__ float bf16_bits_to_f32(unsigned short s) {
    return __uint_as_float(((unsigned)s) << 16);
}

// ---------------- init: zero deg ----------------
__global__ void k_init(int* __restrict__ deg, int n) {
    int i = blockIdx.x * blockDim.x + threadIdx.x;
    int stride = gridDim.x * blockDim.x;
    for (; i < n; i += stride) deg[i] = 0;
}

// ---------------- one-shot weight fragment conversion (1 block) ----------------
__global__ __launch_bounds__(256) void k_wconv(
    const float* __restrict__ w2, const float* __restrict__ l1w,
    const float* __restrict__ l2w,
    short* __restrict__ w2f_hi, short* __restrict__ w2f_lo,
    short* __restrict__ l1f_hi, short* __restrict__ l1f_lo,
    short* __restrict__ l2f_hi, short* __restrict__ l2f_lo)
{
    int t = threadIdx.x;
    int lane = t & 63, combo = t >> 6;
    int lm = lane & 15, lg = lane >> 4;

    {
        int nt = combo >> 1, ks = combo & 1;
        #pragma unroll
        for (int i = 0; i < 8; ++i) {
            float f = w2[(size_t)(ks * 32 + lg * 8 + i) * 32 + nt * 16 + lm];
            unsigned short hb = f32_to_bf16_rne(f);
            float rem = f - bf16_bits_to_f32(hb);
            w2f_hi[((size_t)combo * 64 + lane) * 8 + i] = (short)hb;
            w2f_lo[((size_t)combo * 64 + lane) * 8 + i] = (short)f32_to_bf16_rne(rem);
        }
    }
    {
        int nt = combo;
        #pragma unroll
        for (int i = 0; i < 8; ++i) {
            float f = l1w[(size_t)(nt * 16 + lm) * 32 + lg * 8 + i];
            unsigned short hb = f32_to_bf16_rne(f);
            float rem = f - bf16_bits_to_f32(hb);
            l1f_hi[((size_t)combo * 64 + lane) * 8 + i] = (short)hb;
            l1f_lo[((size_t)combo * 64 + lane) * 8 + i] = (short)f32_to_bf16_rne(rem);
        }
    }
    for (int it = 0; it < 8; ++it) {
        int c = it * 4 + combo;
        int wv = c >> 3, ct = (c >> 1) & 3, ks = c & 1;
        #pragma unroll
        for (int i = 0; i < 8; ++i) {
            float f = l2w[(size_t)(wv * 64 + ct * 16 + lm) * 64 + ks * 32 + lg * 8 + i];
            unsigned short hb = f32_to_bf16_rne(f);
            float rem = f - bf16_bits_to_f32(hb);
            l2f_hi[((size_t)c * 64 + lane) * 8 + i] = (short)hb;
            l2f_lo[((size_t)c * 64 + lane) * 8 + i] = (short)f32_to_bf16_rne(rem);
        }
    }
}

// ---------------- fused: h = feat@w1 (MFMA) blocks  +  deg/rank atomic blocks ----
// Role by blockIdx%5 (interleaved). Feat role stages the A-tile in TWO rounds of
// 32 nodes (LDS 32 KB + 2 KB) so 4 blocks/CU co-reside -> 2x deg waves + 2x feat.
__global__ __launch_bounds__(256) void k_feat_deg(
    const float* __restrict__ feat, const float* __restrict__ w1,
    const float* __restrict__ att_src, const float* __restrict__ att_dst,
    unsigned short* __restrict__ h_bf, float* __restrict__ as_,
    float* __restrict__ ad_,
    const int* __restrict__ ei, int* __restrict__ deg, int* __restrict__ rank,
    int n, int e, int nDegBlocks)
{
    typedef __attribute__((ext_vector_type(8))) short bx8;
    typedef __attribute__((ext_vector_type(4))) float fx4;

    __shared__ short a_hi[2 * 8 * 64 * 8];   // 16 KB (2 mt slots)
    __shared__ short a_lo[2 * 8 * 64 * 8];   // 16 KB
    __shared__ float al_part[2][4][64];      // 2 KB

    int bid = blockIdx.x;
    int grp = bid / 5, pos = bid % 5;
    int t = threadIdx.x, lane = t & 63, wv = t >> 6;

    if (pos == 4) {
        if (grp >= nDegBlocks) return;
        int i = grp * 256 + t;
        int stride = nDegBlocks * 256;
        for (; i < e; i += stride) {
            int d = ei[(size_t)e + i];
            rank[i] = atomicAdd(&deg[d], 1);
        }
        return;
    }

    int fb = grp * 4 + pos;
    int base = fb * 64;
    if (base >= n) return;

    // ---- B (w1) fragments -> registers, hi/lo split ----
    bx8 bhi[8], blo[8];
    {
        int nj = wv * 16 + (lane & 15);
        int kg = (lane >> 4) * 8;
        #pragma unroll
        for (int ks = 0; ks < 8; ++ks) {
            #pragma unroll
            for (int i = 0; i < 8; ++i) {
                float f = w1[(size_t)(ks * 32 + kg + i) * 64 + nj];
                unsigned short hb = f32_to_bf16_rne(f);
                float rem = f - bf16_bits_to_f32(hb);
                bhi[ks][i] = (short)hb;
                blo[ks][i] = (short)f32_to_bf16_rne(rem);
            }
        }
    }

    fx4 acc[4];
    #pragma unroll
    for (int mt = 0; mt < 4; ++mt) acc[mt] = (fx4){0.f, 0.f, 0.f, 0.f};

    #pragma unroll
    for (int rnd = 0; rnd < 2; ++rnd) {
        // ---- stage 32 nodes [rnd*32, rnd*32+32) ----
        float4 v[8];
        #pragma unroll
        for (int c = 0; c < 4; ++c) {
            int node = (t >> 5) + c * 8;       // 0..31 local
            int oct = t & 31;
            int gn = base + rnd * 32 + node;
            if (gn < n) {
                const float4* fp = (const float4*)(feat + (size_t)gn * 256);
                v[2 * c]     = fp[oct * 2];
                v[2 * c + 1] = fp[oct * 2 + 1];
            } else {
                v[2 * c]     = make_float4(0.f, 0.f, 0.f, 0.f);
                v[2 * c + 1] = make_float4(0.f, 0.f, 0.f, 0.f);
            }
        }
        if (rnd == 1) __syncthreads();   // round-0 LDS fully consumed
        #pragma unroll
        for (int c = 0; c < 4; ++c) {
            int node = (t >> 5) + c * 8;
            int oct = t & 31;
            int mtl = node >> 4, lm = node & 15;
            int ks = oct >> 2, lg = oct & 3;
            int flane = lg * 16 + lm;
            int idx = (((mtl * 8 + ks) * 64) + (flane ^ ks)) * 8;
            float ff[8] = { v[2*c].x, v[2*c].y, v[2*c].z, v[2*c].w,
                            v[2*c+1].x, v[2*c+1].y, v[2*c+1].z, v[2*c+1].w };
            bx8 hv, lv;
            #pragma unroll
            for (int i = 0; i < 8; ++i) {
                unsigned short hb = f32_to_bf16_rne(ff[i]);
                float rem = ff[i] - bf16_bits_to_f32(hb);
                hv[i] = (short)hb;
                lv[i] = (short)f32_to_bf16_rne(rem);
            }
            *(bx8*)&a_hi[idx] = hv;
            *(bx8*)&a_lo[idx] = lv;
        }
        __syncthreads();

        // ---- MFMA for this round's 2 row-tiles ----
        #pragma unroll
        for (int mtl = 0; mtl < 2; ++mtl) {
            int mt = rnd * 2 + mtl;
            #pragma unroll
            for (int ks = 0; ks < 8; ++ks) {
                int idx = (((mtl * 8 + ks) * 64) + (lane ^ ks)) * 8;
                bx8 ah = *(bx8*)&a_hi[idx];
                bx8 al = *(bx8*)&a_lo[idx];
                acc[mt] = __builtin_amdgcn_mfma_f32_16x16x32_bf16(ah, bhi[ks], acc[mt], 0, 0, 0);
                acc[mt] = __builtin_amdgcn_mfma_f32_16x16x32_bf16(ah, blo[ks], acc[mt], 0, 0, 0);
                acc[mt] = __builtin_amdgcn_mfma_f32_16x16x32_bf16(al, bhi[ks], acc[mt], 0, 0, 0);
            }
        }
    }

    // ---- epilogue ----
    float asj = att_src[wv * 16 + (lane & 15)];
    float adj = att_dst[wv * 16 + (lane & 15)];
    #pragma unroll
    for (int mt = 0; mt < 4; ++mt) {
        #pragma unroll
        for (int r = 0; r < 4; ++r) {
            int lrow = mt * 16 + (lane >> 4) * 4 + r;
            int node = base + lrow;
            float hv = acc[mt][r];
            if (node < n)
                h_bf[(size_t)node * 64 + wv * 16 + (lane & 15)] = f32_to_bf16_rne(hv);
            float p1 = hv * asj, p2 = hv * adj;
            p1 += __shfl_xor(p1, 1);  p2 += __shfl_xor(p2, 1);
            p1 += __shfl_xor(p1, 2);  p2 += __shfl_xor(p2, 2);
            p1 += __shfl_xor(p1, 4);  p2 += __shfl_xor(p2, 4);
            p1 += __shfl_xor(p1, 8);  p2 += __shfl_xor(p2, 8);
            if ((lane & 15) == 0) {
                al_part[0][wv][lrow] = p1;
                al_part[1][wv][lrow] = p2;
            }
        }
    }
    __syncthreads();
    if (t < 64) {
        int node = base + t;
        if (node < n) {
            as_[node] = al_part[0][0][t] + al_part[0][1][t] + al_part[0][2][t] + al_part[0][3][t];
            ad_[node] = al_part[1][0][t] + al_part[1][1][t] + al_part[1][2][t] + al_part[1][3][t];
        }
    }
}

// ---------------- multi-block exclusive scan, 3 phases ----------------
__global__ __launch_bounds__(1024) void k_scan_part(const int* __restrict__ deg,
                                                    int* __restrict__ part, int n) {
    __shared__ int wlds[16];
    int t = threadIdx.x, lane = t & 63, wv = t >> 6;
    int idx = blockIdx.x * 1024 + t;
    int v = (idx < n) ? deg[idx] : 0;
    #pragma unroll
    for (int s = 32; s > 0; s >>= 1) v += __shfl_xor(v, s);
    if (lane == 0) wlds[wv] = v;
    __syncthreads();
    if (t == 0) {
        int s = 0;
        #pragma unroll
        for (int w = 0; w < 16; ++w) s += wlds[w];
        part[blockIdx.x] = s;
    }
}

__global__ __launch_bounds__(1024) void k_scan_top(int* __restrict__ part,
                                                   int* __restrict__ off,
                                                   int nb, int n) {
    __shared__ int wsum[16];
    int t = threadIdx.x, lane = t & 63, wv = t >> 6;
    int v = (t < nb) ? part[t] : 0;
    int x = v;
    #pragma unroll
    for (int i = 1; i < 64; i <<= 1) {
        int u = __shfl_up(x, i);
        if (lane >= i) x += u;
    }
    if (lane == 63) wsum[wv] = x;
    __syncthreads();
    int add = 0;
    for (int w = 0; w < wv; ++w) add += wsum[w];
    if (t < nb) part[t] = x - v + add;
    if (t == nb - 1) off[n] = x + add;
}

__global__ __launch_bounds__(1024) void k_scan_down(const int* __restrict__ deg,
                                                    const int* __restrict__ part,
                                                    int* __restrict__ off, int n) {
    __shared__ int wsum[16];
    int t = threadIdx.x, lane = t & 63, wv = t >> 6;
    int idx = blockIdx.x * 1024 + t;
    int v = (idx < n) ? deg[idx] : 0;
    int x = v;
    #pragma unroll
    for (int i = 1; i < 64; i <<= 1) {
        int u = __shfl_up(x, i);
        if (lane >= i) x += u;
    }
    if (lane == 63) wsum[wv] = x;
    __syncthreads();
    int add = 0;
    for (int w = 0; w < wv; ++w) add += wsum[w];
    if (idx < n) off[idx] = x - v + add + part[blockIdx.x];
}

// ---------------- fill CSR (no atomics): srcs[pos] = src only ----------------
__global__ void k_fill(const int* __restrict__ ei, const int* __restrict__ off,
                       const int* __restrict__ rank, int* __restrict__ srcs,
                       int e, int lo, int hi) {
    int i = blockIdx.x * blockDim.x + threadIdx.x;
    int stride = gridDim.x * blockDim.x;
    for (; i < e; i += stride) {
        int d = ei[(size_t)e + i];
        if (d < lo || d >= hi) continue;
        srcs[off[d] + rank[i]] = ei[i];
    }
}

// ---------------- fused softmax + aggregate per dst wave -> h1 (bf16) ----------
__global__ __launch_bounds__(256) void k_gat(const int* __restrict__ off,
                                             const int* __restrict__ srcs,
                                             const float* __restrict__ as_,
                                             const float* __restrict__ ad_,
                                             const unsigned short* __restrict__ h_bf,
                                             unsigned short* __restrict__ h1b, int n) {
    int lane = threadIdx.x & 63;
    int d = blockIdx.x * 4 + (threadIdx.x >> 6);
    if (d >= n) return;
    int beg = off[d], end = off[d + 1];
    float adv = ad_[d];
    int cnt = end - beg;
    float a0 = 0.f, a1 = 0.f, a2 = 0.f, a3 = 0.f;

    if (cnt <= 64) {
        int idx = beg + lane;
        bool valid = idx < end;
        int sreg = valid ? srcs[idx] : 0;
        float ev = -3.0e38f;
        if (valid) {
            ev = as_[sreg] + adv;
            ev = ev > 0.f ? ev : NEG_SLOPE * ev;
        }
        float m = ev;
        #pragma unroll
        for (int s = 32; s > 0; s >>= 1) m = fmaxf(m, __shfl_xor(m, s));
        float wu = valid ? __expf(ev - m) : 0.f;
        float z = wu;
        #pragma unroll
        for (int s = 32; s > 0; s >>= 1) z += __shfl_xor(z, s);
        float wreg = wu * (1.f / (z + EPSV));

        int j = 0;
        for (; j + 4 <= cnt; j += 4) {
            int   s0 = __shfl(sreg, j),     s1 = __shfl(sreg, j + 1);
            int   s2 = __shfl(sreg, j + 2), s3 = __shfl(sreg, j + 3);
            float w0 = __shfl(wreg, j),     w1 = __shfl(wreg, j + 1);
            float w2 = __shfl(wreg, j + 2), w3 = __shfl(wreg, j + 3);
            a0 += w0 * bf16_bits_to_f32(h_bf[(size_t)s0 * 64 + lane]);
            a1 += w1 * bf16_bits_to_f32(h_bf[(size_t)s1 * 64 + lane]);
            a2 += w2 * bf16_bits_to_f32(h_bf[(size_t)s2 * 64 + lane]);
            a3 += w3 * bf16_bits_to_f32(h_bf[(size_t)s3 * 64 + lane]);
        }
        for (; j < cnt; ++j) {
            int   sj = __shfl(sreg, j);
            float wj = __shfl(wreg, j);
            a0 += wj * bf16_bits_to_f32(h_bf[(size_t)sj * 64 + lane]);
        }
    } else {
        float m = -3.0e38f;
        for (int i = beg + lane; i < end; i += 64) {
            float ev = as_[srcs[i]] + adv;
            ev = ev > 0.f ? ev : NEG_SLOPE * ev;
            m = fmaxf(m, ev);
        }
        #pragma unroll
        for (int s = 32; s > 0; s >>= 1) m = fmaxf(m, __shfl_xor(m, s));

        float z = 0.f;
        for (int i = beg + lane; i < end; i += 64) {
            float ev = as_[srcs[i]] + adv;
            ev = ev > 0.f ? ev : NEG_SLOPE * ev;
            z += __expf(ev - m);
        }
        #pragma unroll
        for (int s = 32; s > 0; s >>= 1) z += __shfl_xor(z, s);
        float rz = 1.f / (z + EPSV);

        for (int chunk = beg; chunk < end; chunk += 64) {
            int idx = chunk + lane;
            int sreg = 0; float wreg = 0.f;
            if (idx < end) {
                sreg = srcs[idx];
                float ev = as_[sreg] + adv;
                ev = ev > 0.f ? ev : NEG_SLOPE * ev;
                wreg = __expf(ev - m) * rz;
            }
            int ccnt = min(64, end - chunk);
            int j = 0;
            for (; j + 4 <= ccnt; j += 4) {
                int   s0 = __shfl(sreg, j),     s1 = __shfl(sreg, j + 1);
                int   s2 = __shfl(sreg, j + 2), s3 = __shfl(sreg, j + 3);
                float w0 = __shfl(wreg, j),     w1 = __shfl(wreg, j + 1);
                float w2 = __shfl(wreg, j + 2), w3 = __shfl(wreg, j + 3);
                a0 += w0 * bf16_bits_to_f32(h_bf[(size_t)s0 * 64 + lane]);
                a1 += w1 * bf16_bits_to_f32(h_bf[(size_t)s1 * 64 + lane]);
                a2 += w2 * bf16_bits_to_f32(h_bf[(size_t)s2 * 64 + lane]);
                a3 += w3 * bf16_bits_to_f32(h_bf[(size_t)s3 * 64 + lane]);
            }
            for (; j < ccnt; ++j) {
                int   sj = __shfl(sreg, j);
                float wj = __shfl(wreg, j);
                a0 += wj * bf16_bits_to_f32(h_bf[(size_t)sj * 64 + lane]);
            }
        }
    }
    h1b[(size_t)d * 64 + lane] = f32_to_bf16_rne(eluf((a0 + a1) + (a2 + a3)));
}

// ---------------- fused node MLP via MFMA (bf16 h1 in, pre-converted weights) ----
__global__ __launch_bounds__(256) void k_mlp_fused(
    const unsigned short* __restrict__ h1b,
    const short* __restrict__ w2f_hi, const short* __restrict__ w2f_lo,
    const short* __restrict__ l1f_hi, const short* __restrict__ l1f_lo,
    const short* __restrict__ l2f_hi, const short* __restrict__ l2f_lo,
    const float* __restrict__ l1b, const float* __restrict__ l2b,
    float* __restrict__ oh2, float* __restrict__ oh4, int n)
{
    typedef __attribute__((ext_vector_type(8))) short bx8;
    typedef __attribute__((ext_vector_type(4))) float fx4;

    __shared__ float lds2[64 * 36];
    __shared__ float lds3[64 * 68];

    int t = threadIdx.x, lane = t & 63, wv = t >> 6;
    int base = blockIdx.x * 64;
    int lm = lane & 15, lg = lane >> 4;

    fx4 acc2[2];
    acc2[0] = (fx4){0.f, 0.f, 0.f, 0.f};
    acc2[1] = (fx4){0.f, 0.f, 0.f, 0.f};
    {
        bx8 ahi[2];
        int row = base + wv * 16 + lm;
        #pragma unroll
        for (int ks = 0; ks < 2; ++ks) {
            if (row < n)
                ahi[ks] = *(const bx8*)(h1b + (size_t)row * 64 + ks * 32 + lg * 8);
            else
                ahi[ks] = (bx8){0, 0, 0, 0, 0, 0, 0, 0};
        }
        #pragma unroll
        for (int nt = 0; nt < 2; ++nt) {
            #pragma unroll
            for (int ks = 0; ks < 2; ++ks) {
                int c = nt * 2 + ks;
                bx8 bh = *(const bx8*)&w2f_hi[((size_t)c * 64 + lane) * 8];
                bx8 bl = *(const bx8*)&w2f_lo[((size_t)c * 64 + lane) * 8];
                acc2[nt] = __builtin_amdgcn_mfma_f32_16x16x32_bf16(ahi[ks], bh, acc2[nt], 0, 0, 0);
                acc2[nt] = __builtin_amdgcn_mfma_f32_16x16x32_bf16(ahi[ks], bl, acc2[nt], 0, 0, 0);
            }
        }
    }
    #pragma unroll
    for (int nt = 0; nt < 2; ++nt) {
        #pragma unroll
        for (int r = 0; r < 4; ++r) {
            int lrow = wv * 16 + lg * 4 + r;
            int node = base + lrow;
            float v = acc2[nt][r];
            if (node < n) oh2[(size_t)node * 32 + nt * 16 + lm] = v;
            lds2[lrow * 36 + nt * 16 + lm] = v;
        }
    }
    __syncthreads();

    fx4 acc3[4];
    #pragma unroll
    for (int nt = 0; nt < 4; ++nt) acc3[nt] = (fx4){0.f, 0.f, 0.f, 0.f};
    {
        bx8 ahi, alo;
        {
            const float* ap = &lds2[(wv * 16 + lm) * 36 + lg * 8];
            float4 a0 = *(const float4*)ap;
            float4 a1 = *(const float4*)(ap + 4);
            float ff[8] = { a0.x, a0.y, a0.z, a0.w, a1.x, a1.y, a1.z, a1.w };
            #pragma unroll
            for (int i = 0; i < 8; ++i) {
                unsigned short hb = f32_to_bf16_rne(ff[i]);
                float rem = ff[i] - bf16_bits_to_f32(hb);
                ahi[i] = (short)hb;
                alo[i] = (short)f32_to_bf16_rne(rem);
            }
        }
        #pragma unroll
        for (int nt = 0; nt < 4; ++nt) {
            bx8 bh = *(const bx8*)&l1f_hi[((size_t)nt * 64 + lane) * 8];
            bx8 bl = *(const bx8*)&l1f_lo[((size_t)nt * 64 + lane) * 8];
            acc3[nt] = __builtin_amdgcn_mfma_f32_16x16x32_bf16(ahi, bh, acc3[nt], 0, 0, 0);
            acc3[nt] = __builtin_amdgcn_mfma_f32_16x16x32_bf16(ahi, bl, acc3[nt], 0, 0, 0);
            acc3[nt] = __builtin_amdgcn_mfma_f32_16x16x32_bf16(alo, bh, acc3[nt], 0, 0, 0);
        }
    }
    #pragma unroll
    for (int nt = 0; nt < 4; ++nt) {
        float b = l1b[nt * 16 + lm];
        #pragma unroll
        for (int r = 0; r < 4; ++r) {
            int lrow = wv * 16 + lg * 4 + r;
            lds3[lrow * 68 + nt * 16 + lm] = eluf(acc3[nt][r] + b);
        }
    }
    __syncthreads();

    float bias[4];
    #pragma unroll
    for (int ct = 0; ct < 4; ++ct) bias[ct] = l2b[wv * 64 + ct * 16 + lm];

    #pragma unroll
    for (int mt = 0; mt < 4; ++mt) {
        bx8 ahi[2], alo[2];
        #pragma unroll
        for (int ks = 0; ks < 2; ++ks) {
            const float* ap = &lds3[(mt * 16 + lm) * 68 + ks * 32 + lg * 8];
            float4 a0 = *(const float4*)ap;
            float4 a1 = *(const float4*)(ap + 4);
            float ff[8] = { a0.x, a0.y, a0.z, a0.w, a1.x, a1.y, a1.z, a1.w };
            #pragma unroll
            for (int i = 0; i < 8; ++i) {
                unsigned short hb = f32_to_bf16_rne(ff[i]);
                float rem = ff[i] - bf16_bits_to_f32(hb);
                ahi[ks][i] = (short)hb;
                alo[ks][i] = (short)f32_to_bf16_rne(rem);
            }
        }
        fx4 acc[4];
        #pragma unroll
        for (int ct = 0; ct < 4; ++ct) acc[ct] = (fx4){0.f, 0.f, 0.f, 0.f};
        #pragma unroll
        for (int ct = 0; ct < 4; ++ct) {
            #pragma unroll
            for (int ks = 0; ks < 2; ++ks) {
                int c = wv * 8 + ct * 2 + ks;
                bx8 bh = *(const bx8*)&l2f_hi[((size_t)c * 64 + lane) * 8];
                bx8 bl = *(const bx8*)&l2f_lo[((size_t)c * 64 + lane) * 8];
                acc[ct] = __builtin_amdgcn_mfma_f32_16x16x32_bf16(ahi[ks], bh, acc[ct], 0, 0, 0);
                acc[ct] = __builtin_amdgcn_mfma_f32_16x16x32_bf16(ahi[ks], bl, acc[ct], 0, 0, 0);
                acc[ct] = __builtin_amdgcn_mfma_f32_16x16x32_bf16(alo[ks], bh, acc[ct], 0, 0, 0);
            }
        }
        #pragma unroll
        for (int ct = 0; ct < 4; ++ct) {
            #pragma unroll
            for (int r = 0; r < 4; ++r) {
                int orow = base + mt * 16 + lg * 4 + r;
                if (orow < n) {
                    int ocol = wv * 64 + ct * 16 + lm;
                    oh4[(size_t)orow * 256 + ocol] = acc[ct][r] + bias[ct];
                }
            }
        }
    }
}

extern "C" void kernel_launch(void* const* d_in, const int* in_sizes, int n_in,
                              void* d_out, int out_size, void* d_ws, size_t ws_size,
                              hipStream_t stream) {
    const float* feat    = (const float*)d_in[0];
    const int*   ei      = (const int*)d_in[1];     // int64 in ref -> int32 on device
    const float* w1      = (const float*)d_in[2];
    const float* att_src = (const float*)d_in[3];
    const float* att_dst = (const float*)d_in[4];
    const float* w2      = (const float*)d_in[5];
    const float* l1w     = (const float*)d_in[6];
    const float* l1b     = (const float*)d_in[7];
    const float* l2w     = (const float*)d_in[8];
    const float* l2b     = (const float*)d_in[9];

    const int N = in_sizes[0] / IN_DIM;
    const int E = in_sizes[1] / 2;

    char* p = (char*)d_ws;
    auto alloc = [&](size_t bytes) {
        char* r = p;
        p += (bytes + 255) & ~(size_t)255;
        return r;
    };
    unsigned short* h_bf = (unsigned short*)alloc((size_t)N * HID * 2);
    unsigned short* h1b  = (unsigned short*)alloc((size_t)N * HID * 2);
    float* as_   = (float*)alloc((size_t)N * 4);
    float* ad_   = (float*)alloc((size_t)N * 4);
    int*   deg   = (int*)alloc((size_t)N * 4);
    int*   off   = (int*)alloc((size_t)(N + 1) * 4);
    int*   rank  = (int*)alloc((size_t)E * 4);
    int*   srcs  = (int*)alloc((size_t)E * 4);
    const int nb = (N + 1023) / 1024;
    int*   part  = (int*)alloc((size_t)nb * 4);
    short* w2f_hi = (short*)alloc(4 * 64 * 8 * 2);
    short* w2f_lo = (short*)alloc(4 * 64 * 8 * 2);
    short* l1f_hi = (short*)alloc(4 * 64 * 8 * 2);
    short* l1f_lo = (short*)alloc(4 * 64 * 8 * 2);
    short* l2f_hi = (short*)alloc(32 * 64 * 8 * 2);
    short* l2f_lo = (short*)alloc(32 * 64 * 8 * 2);

    float* oh2 = (float*)d_out;
    float* oh4 = oh2 + (size_t)N * OUTD;

    hipLaunchKernelGGL(k_init, dim3(256), dim3(256), 0, stream, deg, N);
    hipLaunchKernelGGL(k_wconv, dim3(1), dim3(256), 0, stream,
                       w2, l1w, l2w, w2f_hi, w2f_lo, l1f_hi, l1f_lo, l2f_hi, l2f_lo);
    // fused feat + deg: groups of 5 blocks (4 feat tiles + 1 deg chunk), interleaved
    const int nDegBlocks = 512;
    const int nFeatTiles = (N + 63) / 64;
    const int nGroups    = max((nFeatTiles + 3) / 4, nDegBlocks);
    hipLaunchKernelGGL(k_feat_deg, dim3(nGroups * 5), dim3(256), 0, stream,
                       feat, w1, att_src, att_dst, h_bf, as_, ad_,
                       ei, deg, rank, N, E, nDegBlocks);
    hipLaunchKernelGGL(k_scan_part, dim3(nb), dim3(1024), 0, stream, deg, part, N);
    hipLaunchKernelGGL(k_scan_top, dim3(1), dim3(1024), 0, stream, part, off, nb, N);
    hipLaunchKernelGGL(k_scan_down, dim3(nb), dim3(1024), 0, stream, deg, part, off, N);
    hipLaunchKernelGGL(k_fill, dim3(2048), dim3(256), 0, stream,
                       ei, off, rank, srcs, E, 0, N);
    hipLaunchKernelGGL(k_gat, dim3((N + 3) / 4), dim3(256), 0, stream,
                       off, srcs, as_, ad_, h_bf, h1b, N);
    hipLaunchKernelGGL(k_mlp_fused, dim3((N + 63) / 64), dim3(256), 0, stream,
                       h1b, w2f_hi, w2f_lo, l1f_hi, l1f_lo, l2f_hi, l2f_lo,
                       l1b, l2b, oh2, oh4, N);
}

// Round 20
// 228.429 us; speedup vs baseline: 1.0459x; 1.0459x over previous
//
#include <hip/hip_runtime.h>
#include <math.h>

constexpr int IN_DIM = 256;
constexpr int HID    = 64;
constexpr int OUTD   = 32;
#define NEG_SLOPE 0.2f
#define EPSV 1e-16f

__device__ __forceinline__ float eluf(float x) {
    return x > 0.f ? x : expm1f(x);
}

__device__ __forceinline__ unsigned short f32_to_bf16_rne(float f) {
    unsigned u = __float_as_uint(f);
    unsigned r = u + 0x7fffu + ((u >> 16) & 1u);
    return (unsigned short)(r >> 16);
}
__device__ __forceinline__ float bf16_bits_to_f32(unsigned short s) {
    return __uint_as_float(((unsigned)s) << 16);
}

// ---------------- init: zero deg ----------------
__global__ void k_init(int* __restrict__ deg, int n) {
    int i = blockIdx.x * blockDim.x + threadIdx.x;
    int stride = gridDim.x * blockDim.x;
    for (; i < n; i += stride) deg[i] = 0;
}

// ---------------- one-shot weight fragment conversion (1 block) ----------------
__global__ __launch_bounds__(256) void k_wconv(
    const float* __restrict__ w2, const float* __restrict__ l1w,
    const float* __restrict__ l2w,
    short* __restrict__ w2f_hi, short* __restrict__ w2f_lo,
    short* __restrict__ l1f_hi, short* __restrict__ l1f_lo,
    short* __restrict__ l2f_hi, short* __restrict__ l2f_lo)
{
    int t = threadIdx.x;
    int lane = t & 63, combo = t >> 6;
    int lm = lane & 15, lg = lane >> 4;

    {
        int nt = combo >> 1, ks = combo & 1;
        #pragma unroll
        for (int i = 0; i < 8; ++i) {
            float f = w2[(size_t)(ks * 32 + lg * 8 + i) * 32 + nt * 16 + lm];
            unsigned short hb = f32_to_bf16_rne(f);
            float rem = f - bf16_bits_to_f32(hb);
            w2f_hi[((size_t)combo * 64 + lane) * 8 + i] = (short)hb;
            w2f_lo[((size_t)combo * 64 + lane) * 8 + i] = (short)f32_to_bf16_rne(rem);
        }
    }
    {
        int nt = combo;
        #pragma unroll
        for (int i = 0; i < 8; ++i) {
            float f = l1w[(size_t)(nt * 16 + lm) * 32 + lg * 8 + i];
            unsigned short hb = f32_to_bf16_rne(f);
            float rem = f - bf16_bits_to_f32(hb);
            l1f_hi[((size_t)combo * 64 + lane) * 8 + i] = (short)hb;
            l1f_lo[((size_t)combo * 64 + lane) * 8 + i] = (short)f32_to_bf16_rne(rem);
        }
    }
    for (int it = 0; it < 8; ++it) {
        int c = it * 4 + combo;
        int wv = c >> 3, ct = (c >> 1) & 3, ks = c & 1;
        #pragma unroll
        for (int i = 0; i < 8; ++i) {
            float f = l2w[(size_t)(wv * 64 + ct * 16 + lm) * 64 + ks * 32 + lg * 8 + i];
            unsigned short hb = f32_to_bf16_rne(f);
            float rem = f - bf16_bits_to_f32(hb);
            l2f_hi[((size_t)c * 64 + lane) * 8 + i] = (short)hb;
            l2f_lo[((size_t)c * 64 + lane) * 8 + i] = (short)f32_to_bf16_rne(rem);
        }
    }
}

// ---------------- fused: h = feat@w1 (MFMA) blocks  +  deg/rank atomic blocks ----
// Role by blockIdx%5 (interleaved). Feat role stages the A-tile in TWO rounds of
// 32 nodes (LDS 32 KB + 2 KB). Deg stream is atomic-fabric-bound (~67 us floor).
__global__ __launch_bounds__(256) void k_feat_deg(
    const float* __restrict__ feat, const float* __restrict__ w1,
    const float* __restrict__ att_src, const float* __restrict__ att_dst,
    unsigned short* __restrict__ h_bf, float* __restrict__ as_,
    float* __restrict__ ad_,
    const int* __restrict__ ei, int* __restrict__ deg, int* __restrict__ rank,
    int n, int e, int nDegBlocks)
{
    typedef __attribute__((ext_vector_type(8))) short bx8;
    typedef __attribute__((ext_vector_type(4))) float fx4;

    __shared__ short a_hi[2 * 8 * 64 * 8];   // 16 KB (2 mt slots)
    __shared__ short a_lo[2 * 8 * 64 * 8];   // 16 KB
    __shared__ float al_part[2][4][64];      // 2 KB

    int bid = blockIdx.x;
    int grp = bid / 5, pos = bid % 5;
    int t = threadIdx.x, lane = t & 63, wv = t >> 6;

    if (pos == 4) {
        if (grp >= nDegBlocks) return;
        int i = grp * 256 + t;
        int stride = nDegBlocks * 256;
        for (; i < e; i += stride) {
            int d = ei[(size_t)e + i];
            rank[i] = atomicAdd(&deg[d], 1);
        }
        return;
    }

    int fb = grp * 4 + pos;
    int base = fb * 64;
    if (base >= n) return;

    // ---- B (w1) fragments -> registers, hi/lo split ----
    bx8 bhi[8], blo[8];
    {
        int nj = wv * 16 + (lane & 15);
        int kg = (lane >> 4) * 8;
        #pragma unroll
        for (int ks = 0; ks < 8; ++ks) {
            #pragma unroll
            for (int i = 0; i < 8; ++i) {
                float f = w1[(size_t)(ks * 32 + kg + i) * 64 + nj];
                unsigned short hb = f32_to_bf16_rne(f);
                float rem = f - bf16_bits_to_f32(hb);
                bhi[ks][i] = (short)hb;
                blo[ks][i] = (short)f32_to_bf16_rne(rem);
            }
        }
    }

    fx4 acc[4];
    #pragma unroll
    for (int mt = 0; mt < 4; ++mt) acc[mt] = (fx4){0.f, 0.f, 0.f, 0.f};

    #pragma unroll
    for (int rnd = 0; rnd < 2; ++rnd) {
        // ---- stage 32 nodes [rnd*32, rnd*32+32) ----
        float4 v[8];
        #pragma unroll
        for (int c = 0; c < 4; ++c) {
            int node = (t >> 5) + c * 8;       // 0..31 local
            int oct = t & 31;
            int gn = base + rnd * 32 + node;
            if (gn < n) {
                const float4* fp = (const float4*)(feat + (size_t)gn * 256);
                v[2 * c]     = fp[oct * 2];
                v[2 * c + 1] = fp[oct * 2 + 1];
            } else {
                v[2 * c]     = make_float4(0.f, 0.f, 0.f, 0.f);
                v[2 * c + 1] = make_float4(0.f, 0.f, 0.f, 0.f);
            }
        }
        if (rnd == 1) __syncthreads();   // round-0 LDS fully consumed
        #pragma unroll
        for (int c = 0; c < 4; ++c) {
            int node = (t >> 5) + c * 8;
            int oct = t & 31;
            int mtl = node >> 4, lm = node & 15;
            int ks = oct >> 2, lg = oct & 3;
            int flane = lg * 16 + lm;
            int idx = (((mtl * 8 + ks) * 64) + (flane ^ ks)) * 8;
            float ff[8] = { v[2*c].x, v[2*c].y, v[2*c].z, v[2*c].w,
                            v[2*c+1].x, v[2*c+1].y, v[2*c+1].z, v[2*c+1].w };
            bx8 hv, lv;
            #pragma unroll
            for (int i = 0; i < 8; ++i) {
                unsigned short hb = f32_to_bf16_rne(ff[i]);
                float rem = ff[i] - bf16_bits_to_f32(hb);
                hv[i] = (short)hb;
                lv[i] = (short)f32_to_bf16_rne(rem);
            }
            *(bx8*)&a_hi[idx] = hv;
            *(bx8*)&a_lo[idx] = lv;
        }
        __syncthreads();

        // ---- MFMA for this round's 2 row-tiles ----
        #pragma unroll
        for (int mtl = 0; mtl < 2; ++mtl) {
            int mt = rnd * 2 + mtl;
            #pragma unroll
            for (int ks = 0; ks < 8; ++ks) {
                int idx = (((mtl * 8 + ks) * 64) + (lane ^ ks)) * 8;
                bx8 ah = *(bx8*)&a_hi[idx];
                bx8 al = *(bx8*)&a_lo[idx];
                acc[mt] = __builtin_amdgcn_mfma_f32_16x16x32_bf16(ah, bhi[ks], acc[mt], 0, 0, 0);
                acc[mt] = __builtin_amdgcn_mfma_f32_16x16x32_bf16(ah, blo[ks], acc[mt], 0, 0, 0);
                acc[mt] = __builtin_amdgcn_mfma_f32_16x16x32_bf16(al, bhi[ks], acc[mt], 0, 0, 0);
            }
        }
    }

    // ---- epilogue ----
    float asj = att_src[wv * 16 + (lane & 15)];
    float adj = att_dst[wv * 16 + (lane & 15)];
    #pragma unroll
    for (int mt = 0; mt < 4; ++mt) {
        #pragma unroll
        for (int r = 0; r < 4; ++r) {
            int lrow = mt * 16 + (lane >> 4) * 4 + r;
            int node = base + lrow;
            float hv = acc[mt][r];
            if (node < n)
                h_bf[(size_t)node * 64 + wv * 16 + (lane & 15)] = f32_to_bf16_rne(hv);
            float p1 = hv * asj, p2 = hv * adj;
            p1 += __shfl_xor(p1, 1);  p2 += __shfl_xor(p2, 1);
            p1 += __shfl_xor(p1, 2);  p2 += __shfl_xor(p2, 2);
            p1 += __shfl_xor(p1, 4);  p2 += __shfl_xor(p2, 4);
            p1 += __shfl_xor(p1, 8);  p2 += __shfl_xor(p2, 8);
            if ((lane & 15) == 0) {
                al_part[0][wv][lrow] = p1;
                al_part[1][wv][lrow] = p2;
            }
        }
    }
    __syncthreads();
    if (t < 64) {
        int node = base + t;
        if (node < n) {
            as_[node] = al_part[0][0][t] + al_part[0][1][t] + al_part[0][2][t] + al_part[0][3][t];
            ad_[node] = al_part[1][0][t] + al_part[1][1][t] + al_part[1][2][t] + al_part[1][3][t];
        }
    }
}

// ---------------- multi-block exclusive scan, 3 phases ----------------
__global__ __launch_bounds__(1024) void k_scan_part(const int* __restrict__ deg,
                                                    int* __restrict__ part, int n) {
    __shared__ int wlds[16];
    int t = threadIdx.x, lane = t & 63, wv = t >> 6;
    int idx = blockIdx.x * 1024 + t;
    int v = (idx < n) ? deg[idx] : 0;
    #pragma unroll
    for (int s = 32; s > 0; s >>= 1) v += __shfl_xor(v, s);
    if (lane == 0) wlds[wv] = v;
    __syncthreads();
    if (t == 0) {
        int s = 0;
        #pragma unroll
        for (int w = 0; w < 16; ++w) s += wlds[w];
        part[blockIdx.x] = s;
    }
}

__global__ __launch_bounds__(1024) void k_scan_top(int* __restrict__ part,
                                                   int* __restrict__ off,
                                                   int nb, int n) {
    __shared__ int wsum[16];
    int t = threadIdx.x, lane = t & 63, wv = t >> 6;
    int v = (t < nb) ? part[t] : 0;
    int x = v;
    #pragma unroll
    for (int i = 1; i < 64; i <<= 1) {
        int u = __shfl_up(x, i);
        if (lane >= i) x += u;
    }
    if (lane == 63) wsum[wv] = x;
    __syncthreads();
    int add = 0;
    for (int w = 0; w < wv; ++w) add += wsum[w];
    if (t < nb) part[t] = x - v + add;
    if (t == nb - 1) off[n] = x + add;
}

__global__ __launch_bounds__(1024) void k_scan_down(const int* __restrict__ deg,
                                                    const int* __restrict__ part,
                                                    int* __restrict__ off, int n) {
    __shared__ int wsum[16];
    int t = threadIdx.x, lane = t & 63, wv = t >> 6;
    int idx = blockIdx.x * 1024 + t;
    int v = (idx < n) ? deg[idx] : 0;
    int x = v;
    #pragma unroll
    for (int i = 1; i < 64; i <<= 1) {
        int u = __shfl_up(x, i);
        if (lane >= i) x += u;
    }
    if (lane == 63) wsum[wv] = x;
    __syncthreads();
    int add = 0;
    for (int w = 0; w < wv; ++w) add += wsum[w];
    if (idx < n) off[idx] = x - v + add + part[blockIdx.x];
}

// ---------------- fill CSR (no atomics): srcs[pos] = src only ----------------
// dst-partitioned passes: scatter target ~1.6 MB/pass stays L2-resident.
__global__ void k_fill(const int* __restrict__ ei, const int* __restrict__ off,
                       const int* __restrict__ rank, int* __restrict__ srcs,
                       int e, int lo, int hi) {
    int i = blockIdx.x * blockDim.x + threadIdx.x;
    int stride = gridDim.x * blockDim.x;
    for (; i < e; i += stride) {
        int d = ei[(size_t)e + i];
        if (d < lo || d >= hi) continue;
        srcs[off[d] + rank[i]] = ei[i];
    }
}

// ---------------- fused softmax + aggregate per dst wave -> h1 (bf16) ----------
__global__ __launch_bounds__(256) void k_gat(const int* __restrict__ off,
                                             const int* __restrict__ srcs,
                                             const float* __restrict__ as_,
                                             const float* __restrict__ ad_,
                                             const unsigned short* __restrict__ h_bf,
                                             unsigned short* __restrict__ h1b, int n) {
    int lane = threadIdx.x & 63;
    int d = blockIdx.x * 4 + (threadIdx.x >> 6);
    if (d >= n) return;
    int beg = off[d], end = off[d + 1];
    float adv = ad_[d];
    int cnt = end - beg;
    float a0 = 0.f, a1 = 0.f, a2 = 0.f, a3 = 0.f;

    if (cnt <= 64) {
        int idx = beg + lane;
        bool valid = idx < end;
        int sreg = valid ? srcs[idx] : 0;
        float ev = -3.0e38f;
        if (valid) {
            ev = as_[sreg] + adv;
            ev = ev > 0.f ? ev : NEG_SLOPE * ev;
        }
        float m = ev;
        #pragma unroll
        for (int s = 32; s > 0; s >>= 1) m = fmaxf(m, __shfl_xor(m, s));
        float wu = valid ? __expf(ev - m) : 0.f;
        float z = wu;
        #pragma unroll
        for (int s = 32; s > 0; s >>= 1) z += __shfl_xor(z, s);
        float wreg = wu * (1.f / (z + EPSV));

        int j = 0;
        for (; j + 4 <= cnt; j += 4) {
            int   s0 = __shfl(sreg, j),     s1 = __shfl(sreg, j + 1);
            int   s2 = __shfl(sreg, j + 2), s3 = __shfl(sreg, j + 3);
            float w0 = __shfl(wreg, j),     w1 = __shfl(wreg, j + 1);
            float w2 = __shfl(wreg, j + 2), w3 = __shfl(wreg, j + 3);
            a0 += w0 * bf16_bits_to_f32(h_bf[(size_t)s0 * 64 + lane]);
            a1 += w1 * bf16_bits_to_f32(h_bf[(size_t)s1 * 64 + lane]);
            a2 += w2 * bf16_bits_to_f32(h_bf[(size_t)s2 * 64 + lane]);
            a3 += w3 * bf16_bits_to_f32(h_bf[(size_t)s3 * 64 + lane]);
        }
        for (; j < cnt; ++j) {
            int   sj = __shfl(sreg, j);
            float wj = __shfl(wreg, j);
            a0 += wj * bf16_bits_to_f32(h_bf[(size_t)sj * 64 + lane]);
        }
    } else {
        float m = -3.0e38f;
        for (int i = beg + lane; i < end; i += 64) {
            float ev = as_[srcs[i]] + adv;
            ev = ev > 0.f ? ev : NEG_SLOPE * ev;
            m = fmaxf(m, ev);
        }
        #pragma unroll
        for (int s = 32; s > 0; s >>= 1) m = fmaxf(m, __shfl_xor(m, s));

        float z = 0.f;
        for (int i = beg + lane; i < end; i += 64) {
            float ev = as_[srcs[i]] + adv;
            ev = ev > 0.f ? ev : NEG_SLOPE * ev;
            z += __expf(ev - m);
        }
        #pragma unroll
        for (int s = 32; s > 0; s >>= 1) z += __shfl_xor(z, s);
        float rz = 1.f / (z + EPSV);

        for (int chunk = beg; chunk < end; chunk += 64) {
            int idx = chunk + lane;
            int sreg = 0; float wreg = 0.f;
            if (idx < end) {
                sreg = srcs[idx];
                float ev = as_[sreg] + adv;
                ev = ev > 0.f ? ev : NEG_SLOPE * ev;
                wreg = __expf(ev - m) * rz;
            }
            int ccnt = min(64, end - chunk);
            int j = 0;
            for (; j + 4 <= ccnt; j += 4) {
                int   s0 = __shfl(sreg, j),     s1 = __shfl(sreg, j + 1);
                int   s2 = __shfl(sreg, j + 2), s3 = __shfl(sreg, j + 3);
                float w0 = __shfl(wreg, j),     w1 = __shfl(wreg, j + 1);
                float w2 = __shfl(wreg, j + 2), w3 = __shfl(wreg, j + 3);
                a0 += w0 * bf16_bits_to_f32(h_bf[(size_t)s0 * 64 + lane]);
                a1 += w1 * bf16_bits_to_f32(h_bf[(size_t)s1 * 64 + lane]);
                a2 += w2 * bf16_bits_to_f32(h_bf[(size_t)s2 * 64 + lane]);
                a3 += w3 * bf16_bits_to_f32(h_bf[(size_t)s3 * 64 + lane]);
            }
            for (; j < ccnt; ++j) {
                int   sj = __shfl(sreg, j);
                float wj = __shfl(wreg, j);
                a0 += wj * bf16_bits_to_f32(h_bf[(size_t)sj * 64 + lane]);
            }
        }
    }
    h1b[(size_t)d * 64 + lane] = f32_to_bf16_rne(eluf((a0 + a1) + (a2 + a3)));
}

// ---------------- fused node MLP via MFMA (bf16 h1 in, pre-converted weights) ----
__global__ __launch_bounds__(256) void k_mlp_fused(
    const unsigned short* __restrict__ h1b,
    const short* __restrict__ w2f_hi, const short* __restrict__ w2f_lo,
    const short* __restrict__ l1f_hi, const short* __restrict__ l1f_lo,
    const short* __restrict__ l2f_hi, const short* __restrict__ l2f_lo,
    const float* __restrict__ l1b, const float* __restrict__ l2b,
    float* __restrict__ oh2, float* __restrict__ oh4, int n)
{
    typedef __attribute__((ext_vector_type(8))) short bx8;
    typedef __attribute__((ext_vector_type(4))) float fx4;

    __shared__ float lds2[64 * 36];
    __shared__ float lds3[64 * 68];

    int t = threadIdx.x, lane = t & 63, wv = t >> 6;
    int base = blockIdx.x * 64;
    int lm = lane & 15, lg = lane >> 4;

    fx4 acc2[2];
    acc2[0] = (fx4){0.f, 0.f, 0.f, 0.f};
    acc2[1] = (fx4){0.f, 0.f, 0.f, 0.f};
    {
        bx8 ahi[2];
        int row = base + wv * 16 + lm;
        #pragma unroll
        for (int ks = 0; ks < 2; ++ks) {
            if (row < n)
                ahi[ks] = *(const bx8*)(h1b + (size_t)row * 64 + ks * 32 + lg * 8);
            else
                ahi[ks] = (bx8){0, 0, 0, 0, 0, 0, 0, 0};
        }
        #pragma unroll
        for (int nt = 0; nt < 2; ++nt) {
            #pragma unroll
            for (int ks = 0; ks < 2; ++ks) {
                int c = nt * 2 + ks;
                bx8 bh = *(const bx8*)&w2f_hi[((size_t)c * 64 + lane) * 8];
                bx8 bl = *(const bx8*)&w2f_lo[((size_t)c * 64 + lane) * 8];
                acc2[nt] = __builtin_amdgcn_mfma_f32_16x16x32_bf16(ahi[ks], bh, acc2[nt], 0, 0, 0);
                acc2[nt] = __builtin_amdgcn_mfma_f32_16x16x32_bf16(ahi[ks], bl, acc2[nt], 0, 0, 0);
            }
        }
    }
    #pragma unroll
    for (int nt = 0; nt < 2; ++nt) {
        #pragma unroll
        for (int r = 0; r < 4; ++r) {
            int lrow = wv * 16 + lg * 4 + r;
            int node = base + lrow;
            float v = acc2[nt][r];
            if (node < n) oh2[(size_t)node * 32 + nt * 16 + lm] = v;
            lds2[lrow * 36 + nt * 16 + lm] = v;
        }
    }
    __syncthreads();

    fx4 acc3[4];
    #pragma unroll
    for (int nt = 0; nt < 4; ++nt) acc3[nt] = (fx4){0.f, 0.f, 0.f, 0.f};
    {
        bx8 ahi, alo;
        {
            const float* ap = &lds2[(wv * 16 + lm) * 36 + lg * 8];
            float4 a0 = *(const float4*)ap;
            float4 a1 = *(const float4*)(ap + 4);
            float ff[8] = { a0.x, a0.y, a0.z, a0.w, a1.x, a1.y, a1.z, a1.w };
            #pragma unroll
            for (int i = 0; i < 8; ++i) {
                unsigned short hb = f32_to_bf16_rne(ff[i]);
                float rem = ff[i] - bf16_bits_to_f32(hb);
                ahi[i] = (short)hb;
                alo[i] = (short)f32_to_bf16_rne(rem);
            }
        }
        #pragma unroll
        for (int nt = 0; nt < 4; ++nt) {
            bx8 bh = *(const bx8*)&l1f_hi[((size_t)nt * 64 + lane) * 8];
            bx8 bl = *(const bx8*)&l1f_lo[((size_t)nt * 64 + lane) * 8];
            acc3[nt] = __builtin_amdgcn_mfma_f32_16x16x32_bf16(ahi, bh, acc3[nt], 0, 0, 0);
            acc3[nt] = __builtin_amdgcn_mfma_f32_16x16x32_bf16(ahi, bl, acc3[nt], 0, 0, 0);
            acc3[nt] = __builtin_amdgcn_mfma_f32_16x16x32_bf16(alo, bh, acc3[nt], 0, 0, 0);
        }
    }
    #pragma unroll
    for (int nt = 0; nt < 4; ++nt) {
        float b = l1b[nt * 16 + lm];
        #pragma unroll
        for (int r = 0; r < 4; ++r) {
            int lrow = wv * 16 + lg * 4 + r;
            lds3[lrow * 68 + nt * 16 + lm] = eluf(acc3[nt][r] + b);
        }
    }
    __syncthreads();

    float bias[4];
    #pragma unroll
    for (int ct = 0; ct < 4; ++ct) bias[ct] = l2b[wv * 64 + ct * 16 + lm];

    #pragma unroll
    for (int mt = 0; mt < 4; ++mt) {
        bx8 ahi[2], alo[2];
        #pragma unroll
        for (int ks = 0; ks < 2; ++ks) {
            const float* ap = &lds3[(mt * 16 + lm) * 68 + ks * 32 + lg * 8];
            float4 a0 = *(const float4*)ap;
            float4 a1 = *(const float4*)(ap + 4);
            float ff[8] = { a0.x, a0.y, a0.z, a0.w, a1.x, a1.y, a1.z, a1.w };
            #pragma unroll
            for (int i = 0; i < 8; ++i) {
                unsigned short hb = f32_to_bf16_rne(ff[i]);
                float rem = ff[i] - bf16_bits_to_f32(hb);
                ahi[ks][i] = (short)hb;
                alo[ks][i] = (short)f32_to_bf16_rne(rem);
            }
        }
        fx4 acc[4];
        #pragma unroll
        for (int ct = 0; ct < 4; ++ct) acc[ct] = (fx4){0.f, 0.f, 0.f, 0.f};
        #pragma unroll
        for (int ct = 0; ct < 4; ++ct) {
            #pragma unroll
            for (int ks = 0; ks < 2; ++ks) {
                int c = wv * 8 + ct * 2 + ks;
                bx8 bh = *(const bx8*)&l2f_hi[((size_t)c * 64 + lane) * 8];
                bx8 bl = *(const bx8*)&l2f_lo[((size_t)c * 64 + lane) * 8];
                acc[ct] = __builtin_amdgcn_mfma_f32_16x16x32_bf16(ahi[ks], bh, acc[ct], 0, 0, 0);
                acc[ct] = __builtin_amdgcn_mfma_f32_16x16x32_bf16(ahi[ks], bl, acc[ct], 0, 0, 0);
                acc[ct] = __builtin_amdgcn_mfma_f32_16x16x32_bf16(alo[ks], bh, acc[ct], 0, 0, 0);
            }
        }
        #pragma unroll
        for (int ct = 0; ct < 4; ++ct) {
            #pragma unroll
            for (int r = 0; r < 4; ++r) {
                int orow = base + mt * 16 + lg * 4 + r;
                if (orow < n) {
                    int ocol = wv * 64 + ct * 16 + lm;
                    oh4[(size_t)orow * 256 + ocol] = acc[ct][r] + bias[ct];
                }
            }
        }
    }
}

extern "C" void kernel_launch(void* const* d_in, const int* in_sizes, int n_in,
                              void* d_out, int out_size, void* d_ws, size_t ws_size,
                              hipStream_t stream) {
    const float* feat    = (const float*)d_in[0];
    const int*   ei      = (const int*)d_in[1];     // int64 in ref -> int32 on device
    const float* w1      = (const float*)d_in[2];
    const float* att_src = (const float*)d_in[3];
    const float* att_dst = (const float*)d_in[4];
    const float* w2      = (const float*)d_in[5];
    const float* l1w     = (const float*)d_in[6];
    const float* l1b     = (const float*)d_in[7];
    const float* l2w     = (const float*)d_in[8];
    const float* l2b     = (const float*)d_in[9];

    const int N = in_sizes[0] / IN_DIM;
    const int E = in_sizes[1] / 2;

    char* p = (char*)d_ws;
    auto alloc = [&](size_t bytes) {
        char* r = p;
        p += (bytes + 255) & ~(size_t)255;
        return r;
    };
    unsigned short* h_bf = (unsigned short*)alloc((size_t)N * HID * 2);
    unsigned short* h1b  = (unsigned short*)alloc((size_t)N * HID * 2);
    float* as_   = (float*)alloc((size_t)N * 4);
    float* ad_   = (float*)alloc((size_t)N * 4);
    int*   deg   = (int*)alloc((size_t)N * 4);
    int*   off   = (int*)alloc((size_t)(N + 1) * 4);
    int*   rank  = (int*)alloc((size_t)E * 4);
    int*   srcs  = (int*)alloc((size_t)E * 4);
    const int nb = (N + 1023) / 1024;
    int*   part  = (int*)alloc((size_t)nb * 4);
    short* w2f_hi = (short*)alloc(4 * 64 * 8 * 2);
    short* w2f_lo = (short*)alloc(4 * 64 * 8 * 2);
    short* l1f_hi = (short*)alloc(4 * 64 * 8 * 2);
    short* l1f_lo = (short*)alloc(4 * 64 * 8 * 2);
    short* l2f_hi = (short*)alloc(32 * 64 * 8 * 2);
    short* l2f_lo = (short*)alloc(32 * 64 * 8 * 2);

    float* oh2 = (float*)d_out;
    float* oh4 = oh2 + (size_t)N * OUTD;

    hipLaunchKernelGGL(k_init, dim3(256), dim3(256), 0, stream, deg, N);
    hipLaunchKernelGGL(k_wconv, dim3(1), dim3(256), 0, stream,
                       w2, l1w, l2w, w2f_hi, w2f_lo, l1f_hi, l1f_lo, l2f_hi, l2f_lo);
    // fused feat + deg: groups of 5 blocks (4 feat tiles + 1 deg chunk), interleaved
    const int nDegBlocks = 512;
    const int nFeatTiles = (N + 63) / 64;
    const int nGroups    = max((nFeatTiles + 3) / 4, nDegBlocks);
    hipLaunchKernelGGL(k_feat_deg, dim3(nGroups * 5), dim3(256), 0, stream,
                       feat, w1, att_src, att_dst, h_bf, as_, ad_,
                       ei, deg, rank, N, E, nDegBlocks);
    hipLaunchKernelGGL(k_scan_part, dim3(nb), dim3(1024), 0, stream, deg, part, N);
    hipLaunchKernelGGL(k_scan_top, dim3(1), dim3(1024), 0, stream, part, off, nb, N);
    hipLaunchKernelGGL(k_scan_down, dim3(nb), dim3(1024), 0, stream, deg, part, off, N);
    for (int pass = 0; pass < 4; ++pass) {
        int lo = (int)((size_t)N * pass / 4);
        int hi = (int)((size_t)N * (pass + 1) / 4);
        hipLaunchKernelGGL(k_fill, dim3(2048), dim3(256), 0, stream,
                           ei, off, rank, srcs, E, lo, hi);
    }
    hipLaunchKernelGGL(k_gat, dim3((N + 3) / 4), dim3(256), 0, stream,
                       off, srcs, as_, ad_, h_bf, h1b, N);
    hipLaunchKernelGGL(k_mlp_fused, dim3((N + 63) / 64), dim3(256), 0, stream,
                       h1b, w2f_hi, w2f_lo, l1f_hi, l1f_lo, l2f_hi, l2f_lo,
                       l1b, l2b, oh2, oh4, N);
}